// Round 1
// baseline (2074.963 us; speedup 1.0000x reference)
//
#include <hip/hip_runtime.h>
#include <math.h>

// Problem constants (B=8, N=2048, Fin=Fout=512), all fp32.
#define BB 8
#define NN 2048
#define FF 512

// Tiled GEMM config
#define TBM 64
#define TBN 64
#define TBK 16

// Generic stride-parameterized GEMM:
//   C[i,j] = sum_k A[i*lda_i + k*lda_k] * B[k*ldb_k + j*ldb_j]  (+ bias[j])
// One of {lda_i, lda_k} must be 1; one of {ldb_k, ldb_j} must be 1 (for coalesced staging).
// C is row-major M x Nc with leading dim ldc. blockIdx.z = batch.
__global__ __launch_bounds__(256) void gemm_generic(
    const float* __restrict__ A, const float* __restrict__ B,
    float* __restrict__ C, const float* __restrict__ bias,
    int M, int Nc, int K, int ldc,
    long lda_i, long lda_k, long ldb_k, long ldb_j,
    long a_batch, long b_batch, long c_batch)
{
    // +4 pad keeps float4 alignment (row stride 68 floats = 272B, 16B aligned)
    // and gives <=2-way bank aliasing on the staging writes (free on CDNA4).
    __shared__ float As[TBK][TBM + 4];
    __shared__ float Bs[TBK][TBN + 4];

    const int bz = blockIdx.z;
    const float* Ab = A + (long)bz * a_batch;
    const float* Bb = B + (long)bz * b_batch;
    float* Cb = C + (long)bz * c_batch;

    const int m0 = blockIdx.y * TBM;
    const int n0 = blockIdx.x * TBN;
    const int tid = threadIdx.x;
    const int c = tid & 15;   // 0..15 -> 4 cols each
    const int r = tid >> 4;   // 0..15 -> 4 rows each

    float acc[4][4] = {};

    for (int k0 = 0; k0 < K; k0 += TBK) {
        // ---- stage A tile (TBK x TBM), store transposed As[kk][mm] ----
        if (lda_k == 1) {
            // memory fast dim = k
            for (int t = tid; t < TBK * TBM; t += 256) {
                int kk = t & (TBK - 1);
                int mm = t / TBK;
                As[kk][mm] = Ab[(long)(m0 + mm) * lda_i + (k0 + kk)];
            }
        } else {
            // lda_i == 1: memory fast dim = i
            for (int t = tid; t < TBK * TBM; t += 256) {
                int mm = t & (TBM - 1);
                int kk = t / TBM;
                As[kk][mm] = Ab[(long)(m0 + mm) + (long)(k0 + kk) * lda_k];
            }
        }
        // ---- stage B tile (TBK x TBN) as Bs[kk][jj] ----
        if (ldb_j == 1) {
            for (int t = tid; t < TBK * TBN; t += 256) {
                int jj = t & (TBN - 1);
                int kk = t / TBN;
                Bs[kk][jj] = Bb[(long)(k0 + kk) * ldb_k + (n0 + jj)];
            }
        } else {
            // ldb_k == 1
            for (int t = tid; t < TBK * TBN; t += 256) {
                int kk = t & (TBK - 1);
                int jj = t / TBK;
                Bs[kk][jj] = Bb[(long)(k0 + kk) + (long)(n0 + jj) * ldb_j];
            }
        }
        __syncthreads();

        #pragma unroll
        for (int kk = 0; kk < TBK; ++kk) {
            float4 a4 = *(const float4*)&As[kk][r * 4];
            float4 b4 = *(const float4*)&Bs[kk][c * 4];
            float a[4] = {a4.x, a4.y, a4.z, a4.w};
            float b[4] = {b4.x, b4.y, b4.z, b4.w};
            #pragma unroll
            for (int i = 0; i < 4; ++i)
                #pragma unroll
                for (int j = 0; j < 4; ++j)
                    acc[i][j] = fmaf(a[i], b[j], acc[i][j]);
        }
        __syncthreads();
    }

    // ---- epilogue: float4 stores, optional bias ----
    float badd[4] = {0.f, 0.f, 0.f, 0.f};
    if (bias) {
        int n = n0 + c * 4;
        badd[0] = bias[n]; badd[1] = bias[n + 1];
        badd[2] = bias[n + 2]; badd[3] = bias[n + 3];
    }
    #pragma unroll
    for (int i = 0; i < 4; ++i) {
        int m = m0 + r * 4 + i;
        float4 v;
        v.x = acc[i][0] + badd[0];
        v.y = acc[i][1] + badd[1];
        v.z = acc[i][2] + badd[2];
        v.w = acc[i][3] + badd[3];
        *(float4*)&Cb[(long)m * ldc + n0 + c * 4] = v;
    }
}

// Row softmax over rows of length rowlen. blockIdx.x = global row.
__global__ __launch_bounds__(256) void softmax_rows(float* __restrict__ S, int rowlen)
{
    float* row = S + (size_t)blockIdx.x * rowlen;
    const int tid = threadIdx.x;
    __shared__ float red[4];
    __shared__ float bc;

    float lmax = -3.4e38f;
    for (int i = tid; i < rowlen; i += 256) lmax = fmaxf(lmax, row[i]);
    #pragma unroll
    for (int off = 32; off >= 1; off >>= 1) lmax = fmaxf(lmax, __shfl_down(lmax, off));
    if ((tid & 63) == 0) red[tid >> 6] = lmax;
    __syncthreads();
    if (tid == 0) bc = fmaxf(fmaxf(red[0], red[1]), fmaxf(red[2], red[3]));
    __syncthreads();
    const float rmax = bc;

    float lsum = 0.f;
    for (int i = tid; i < rowlen; i += 256) {
        float e = __expf(row[i] - rmax);
        row[i] = e;
        lsum += e;
    }
    #pragma unroll
    for (int off = 32; off >= 1; off >>= 1) lsum += __shfl_down(lsum, off);
    __syncthreads();  // protect red[] reuse
    if ((tid & 63) == 0) red[tid >> 6] = lsum;
    __syncthreads();
    if (tid == 0) bc = 1.0f / (red[0] + red[1] + red[2] + red[3]);
    __syncthreads();
    const float inv = bc;
    for (int i = tid; i < rowlen; i += 256) row[i] *= inv;
}

extern "C" void kernel_launch(void* const* d_in, const int* in_sizes, int n_in,
                              void* d_out, int out_size, void* d_ws, size_t ws_size,
                              hipStream_t stream)
{
    const float* x      = (const float*)d_in[0];  // [8,2048,512]
    const float* weight = (const float*)d_in[1];  // [512,512]
    const float* bias   = (const float*)d_in[2];  // [512]
    const float* w_one  = (const float*)d_in[3];  // [512,512]
    const float* w_two  = (const float*)d_in[4];  // [512,512]
    float* out = (float*)d_out;                   // [8,2048,512]

    const long NF = (long)NN * FF;        // 1,048,576
    const long NN2 = (long)NN * NN;       // 4,194,304
    const size_t sup_elems = (size_t)BB * NF;

    float* ws = (float*)d_ws;
    dim3 blk(256);

    const size_t need_full  = (3 * sup_elems + (size_t)BB * NN2) * sizeof(float); // ~224 MiB
    const size_t need_batch = (3 * sup_elems + (size_t)NN2) * sizeof(float);      // ~117 MiB

    if (ws_size >= need_full) {
        float* support = ws;
        float* p1 = support + sup_elems;
        float* p2 = p1 + sup_elems;
        float* S  = p2 + sup_elems;

        // support = x @ weight          [B,N,F]
        gemm_generic<<<dim3(FF / TBN, NN / TBM, BB), blk, 0, stream>>>(
            x, weight, support, nullptr, NN, FF, FF, FF,
            FF, 1, FF, 1, NF, 0, NF);
        // p1 = x @ w_one^T              [B,N,F]  (p1[n,e] = sum_f x[n,f] w1[e,f])
        gemm_generic<<<dim3(FF / TBN, NN / TBM, BB), blk, 0, stream>>>(
            x, w_one, p1, nullptr, NN, FF, FF, FF,
            FF, 1, 1, FF, NF, 0, NF);
        // p2 = x @ w_two^T              [B,N,F]
        gemm_generic<<<dim3(FF / TBN, NN / TBM, BB), blk, 0, stream>>>(
            x, w_two, p2, nullptr, NN, FF, FF, FF,
            FF, 1, 1, FF, NF, 0, NF);
        // S = adj^T = p2 @ p1^T         [B,N,N]  (S[m,n] = sum_e p2[m,e] p1[n,e])
        gemm_generic<<<dim3(NN / TBN, NN / TBM, BB), blk, 0, stream>>>(
            p2, p1, S, nullptr, NN, NN, FF, NN,
            FF, 1, 1, FF, NF, NF, NN2);
        // softmax along rows of S  == softmax over adj axis=1
        softmax_rows<<<dim3(BB * NN), blk, 0, stream>>>(S, NN);
        // out = S^T @ support + bias    [B,N,F]  (out[n,o] = sum_m S[m,n] sup[m,o])
        gemm_generic<<<dim3(FF / TBN, NN / TBM, BB), blk, 0, stream>>>(
            S, support, out, bias, NN, FF, NN, FF,
            1, NN, FF, 1, NN2, NF, NF);
    } else if (ws_size >= need_batch) {
        float* support = ws;
        float* p1 = support + sup_elems;
        float* p2 = p1 + sup_elems;
        float* S  = p2 + sup_elems;

        gemm_generic<<<dim3(FF / TBN, NN / TBM, BB), blk, 0, stream>>>(
            x, weight, support, nullptr, NN, FF, FF, FF,
            FF, 1, FF, 1, NF, 0, NF);
        gemm_generic<<<dim3(FF / TBN, NN / TBM, BB), blk, 0, stream>>>(
            x, w_one, p1, nullptr, NN, FF, FF, FF,
            FF, 1, 1, FF, NF, 0, NF);
        gemm_generic<<<dim3(FF / TBN, NN / TBM, BB), blk, 0, stream>>>(
            x, w_two, p2, nullptr, NN, FF, FF, FF,
            FF, 1, 1, FF, NF, 0, NF);
        for (int b = 0; b < BB; ++b) {
            gemm_generic<<<dim3(NN / TBN, NN / TBM, 1), blk, 0, stream>>>(
                p2 + (long)b * NF, p1 + (long)b * NF, S, nullptr, NN, NN, FF, NN,
                FF, 1, 1, FF, 0, 0, 0);
            softmax_rows<<<dim3(NN), blk, 0, stream>>>(S, NN);
            gemm_generic<<<dim3(FF / TBN, NN / TBM, 1), blk, 0, stream>>>(
                S, support + (long)b * NF, out + (long)b * NF, bias, NN, FF, NN, FF,
                1, NN, FF, 1, 0, 0, 0);
        }
    } else {
        // fully per-batch: needs (3*N*F + N*N)*4 ~= 29 MiB
        float* support = ws;
        float* p1 = support + NF;
        float* p2 = p1 + NF;
        float* S  = p2 + NF;
        for (int b = 0; b < BB; ++b) {
            const float* xb = x + (long)b * NF;
            gemm_generic<<<dim3(FF / TBN, NN / TBM, 1), blk, 0, stream>>>(
                xb, weight, support, nullptr, NN, FF, FF, FF,
                FF, 1, FF, 1, 0, 0, 0);
            gemm_generic<<<dim3(FF / TBN, NN / TBM, 1), blk, 0, stream>>>(
                xb, w_one, p1, nullptr, NN, FF, FF, FF,
                FF, 1, 1, FF, 0, 0, 0);
            gemm_generic<<<dim3(FF / TBN, NN / TBM, 1), blk, 0, stream>>>(
                xb, w_two, p2, nullptr, NN, FF, FF, FF,
                FF, 1, 1, FF, 0, 0, 0);
            gemm_generic<<<dim3(NN / TBN, NN / TBM, 1), blk, 0, stream>>>(
                p2, p1, S, nullptr, NN, NN, FF, NN,
                FF, 1, 1, FF, 0, 0, 0);
            softmax_rows<<<dim3(NN), blk, 0, stream>>>(S, NN);
            gemm_generic<<<dim3(FF / TBN, NN / TBM, 1), blk, 0, stream>>>(
                S, support, out + (long)b * NF, bias, NN, FF, NN, FF,
                1, NN, FF, 1, 0, 0, 0);
        }
    }
}

// Round 2
// 733.633 us; speedup vs baseline: 2.8283x; 2.8283x over previous
//
#include <hip/hip_runtime.h>
#include <math.h>

// B=8, N=2048, Fin=Fout=512, fp32 in/out. bf16 MFMA internally.
#define BB 8
#define NN 2048
#define FF 512

typedef __attribute__((ext_vector_type(8))) short short8;
typedef __attribute__((ext_vector_type(4))) float floatx4;

__device__ __forceinline__ unsigned short f2bf(float f) {
    union { float f; unsigned u; } v; v.f = f;
    unsigned r = v.u + 0x7FFFu + ((v.u >> 16) & 1u);
    return (unsigned short)(r >> 16);
}

// ---------------------------------------------------------------------------
// BT-GEMM, bf16 MFMA (m97 structure): C[i,j] = sum_k A[i,k]*B[j,k] (+bias[j])
// A: [M x K] bf16 K-fast (lda=K). B: [Nc x K] bf16 K-fast (ldb=K).
// C row-major [M x Nc] (ldc=Nc), fp32 or bf16. blockIdx.z = batch.
// 128x128 tile, BK=32, 256 thr = 4 waves (2x2), 4x4 16x16x32 frags per wave.
// ---------------------------------------------------------------------------
__global__ __launch_bounds__(256) void gemm_mfma_bt(
    const unsigned short* __restrict__ A, const unsigned short* __restrict__ B,
    void* __restrict__ Cv, const float* __restrict__ bias,
    int M, int Nc, int K,
    long a_batch, long b_batch, long c_batch, int c_bf16)
{
    __shared__ __align__(16) unsigned short Alds[128 * 32];
    __shared__ __align__(16) unsigned short Blds[128 * 32];

    const int tid  = threadIdx.x;
    const int wave = tid >> 6;
    const int lane = tid & 63;
    const int bz   = blockIdx.z;

    const unsigned short* Ab = A + (long)bz * a_batch;
    const unsigned short* Bb = B + (long)bz * b_batch;

    const int m0 = blockIdx.y * 128;
    const int n0 = blockIdx.x * 128;

    const int wm   = (wave >> 1) * 64;
    const int wn   = (wave & 1) * 64;
    const int fl   = lane & 15;
    const int quad = lane >> 4;

    floatx4 acc[4][4] = {};

    for (int k0 = 0; k0 < K; k0 += 32) {
        // stage A and B tiles: 128 rows x 32 k bf16 = 8 KB each = 512 x 16B chunks.
        // chunk c -> row c>>2, k-quad c&3; LDS dest = wave-uniform base + lane*16.
        #pragma unroll
        for (int issue = 0; issue < 2; ++issue) {
            const int cbase = issue * 256 + wave * 64;
            const int c = cbase + lane;
            const int row = c >> 2, kq = (c & 3) * 8;
            const unsigned short* gA = Ab + (long)(m0 + row) * K + k0 + kq;
            __builtin_amdgcn_global_load_lds(
                (const __attribute__((address_space(1))) void*)gA,
                (__attribute__((address_space(3))) void*)&Alds[cbase * 8], 16, 0, 0);
            const unsigned short* gB = Bb + (long)(n0 + row) * K + k0 + kq;
            __builtin_amdgcn_global_load_lds(
                (const __attribute__((address_space(1))) void*)gB,
                (__attribute__((address_space(3))) void*)&Blds[cbase * 8], 16, 0, 0);
        }
        __syncthreads();

        short8 af[4], bf[4];
        #pragma unroll
        for (int i = 0; i < 4; ++i)
            af[i] = *(const short8*)&Alds[(wm + i * 16 + fl) * 32 + quad * 8];
        #pragma unroll
        for (int j = 0; j < 4; ++j)
            bf[j] = *(const short8*)&Blds[(wn + j * 16 + fl) * 32 + quad * 8];

        #pragma unroll
        for (int i = 0; i < 4; ++i)
            #pragma unroll
            for (int j = 0; j < 4; ++j)
                acc[i][j] = __builtin_amdgcn_mfma_f32_16x16x32_bf16(af[i], bf[j], acc[i][j], 0, 0, 0);
        __syncthreads();
    }

    // epilogue. C/D layout: col = lane&15, row = quad*4 + reg (verified m89/m91).
    const long ldc = Nc;
    if (!c_bf16) {
        float* Cb = (float*)Cv + (long)bz * c_batch;
        #pragma unroll
        for (int j = 0; j < 4; ++j) {
            const int ng = n0 + wn + j * 16 + fl;
            const float badd = bias ? bias[ng] : 0.0f;
            #pragma unroll
            for (int i = 0; i < 4; ++i) {
                const int mg = m0 + wm + i * 16 + quad * 4;
                #pragma unroll
                for (int r = 0; r < 4; ++r)
                    Cb[(long)(mg + r) * ldc + ng] = acc[i][j][r] + badd;
            }
        }
    } else {
        unsigned short* Cb = (unsigned short*)Cv + (long)bz * c_batch;
        #pragma unroll
        for (int j = 0; j < 4; ++j) {
            const int ng = n0 + wn + j * 16 + fl;
            #pragma unroll
            for (int i = 0; i < 4; ++i) {
                const int mg = m0 + wm + i * 16 + quad * 4;
                #pragma unroll
                for (int r = 0; r < 4; ++r)
                    Cb[(long)(mg + r) * ldc + ng] = f2bf(acc[i][j][r]);
            }
        }
    }
}

// elementwise fp32 -> bf16, 8 elems/thread
__global__ __launch_bounds__(256) void convert_bf16(
    const float* __restrict__ in, unsigned short* __restrict__ out, long n)
{
    long i = ((long)blockIdx.x * 256 + threadIdx.x) * 8;
    if (i + 8 > n) return;
    float4 a = *(const float4*)(in + i);
    float4 b = *(const float4*)(in + i + 4);
    short8 o;
    o[0] = (short)f2bf(a.x); o[1] = (short)f2bf(a.y);
    o[2] = (short)f2bf(a.z); o[3] = (short)f2bf(a.w);
    o[4] = (short)f2bf(b.x); o[5] = (short)f2bf(b.y);
    o[6] = (short)f2bf(b.z); o[7] = (short)f2bf(b.w);
    *(short8*)(out + i) = o;
}

// out[o,f] = bf16(in[f,o]) for a dim x dim fp32 matrix (dim % 32 == 0)
__global__ __launch_bounds__(256) void transpose_convert(
    const float* __restrict__ in, unsigned short* __restrict__ out, int dim)
{
    __shared__ float t[32][33];
    const int tx = threadIdx.x & 31, ty = threadIdx.x >> 5;  // 32x8
    const int x0 = blockIdx.x * 32, y0 = blockIdx.y * 32;
    #pragma unroll
    for (int k = 0; k < 32; k += 8)
        t[ty + k][tx] = in[(long)(y0 + ty + k) * dim + x0 + tx];
    __syncthreads();
    #pragma unroll
    for (int k = 0; k < 32; k += 8)
        out[(long)(x0 + ty + k) * dim + y0 + tx] = f2bf(t[tx][ty + k]);
}

// per-row max and 1/sum(exp(v-max)) of fp32 S rows. stats[0..R)=max, [R..2R)=inv.
__global__ __launch_bounds__(256) void row_stats(
    const float* __restrict__ S, float* __restrict__ stats, int rowlen)
{
    const float* row = S + (size_t)blockIdx.x * rowlen;
    const int tid = threadIdx.x;
    __shared__ float red[8];

    float lmax = -3.4e38f;
    for (int i = tid * 4; i < rowlen; i += 1024) {
        float4 v = *(const float4*)(row + i);
        lmax = fmaxf(fmaxf(fmaxf(lmax, v.x), fmaxf(v.y, v.z)), v.w);
    }
    #pragma unroll
    for (int off = 32; off >= 1; off >>= 1) lmax = fmaxf(lmax, __shfl_down(lmax, off));
    if (!(tid & 63)) red[tid >> 6] = lmax;
    __syncthreads();
    const float rmax = fmaxf(fmaxf(red[0], red[1]), fmaxf(red[2], red[3]));

    float lsum = 0.f;
    for (int i = tid * 4; i < rowlen; i += 1024) {
        float4 v = *(const float4*)(row + i);
        lsum += __expf(v.x - rmax) + __expf(v.y - rmax) + __expf(v.z - rmax) + __expf(v.w - rmax);
    }
    #pragma unroll
    for (int off = 32; off >= 1; off >>= 1) lsum += __shfl_down(lsum, off);
    if (!(tid & 63)) red[4 + (tid >> 6)] = lsum;
    __syncthreads();
    if (tid == 0) {
        stats[blockIdx.x] = rmax;
        stats[gridDim.x + blockIdx.x] = 1.0f / (red[4] + red[5] + red[6] + red[7]);
    }
}

// P[n,m] = bf16(exp(S[m,n]-max[m]) * inv[m]); 32x32 LDS transpose tiles.
// blockIdx.z = batch (S,P stride NN*NN; stats row index = z*NN + m).
__global__ __launch_bounds__(256) void softmax_transpose(
    const float* __restrict__ S, const float* __restrict__ stats,
    unsigned short* __restrict__ P, int statR)
{
    __shared__ float t[32][33];
    const int tx = threadIdx.x & 31, ty = threadIdx.x >> 5;
    const int mt = blockIdx.y * 32, nt = blockIdx.x * 32;
    const float* Sb = S + (size_t)blockIdx.z * NN * NN;
    unsigned short* Pb = P + (size_t)blockIdx.z * NN * NN;
    #pragma unroll
    for (int k = 0; k < 32; k += 8) {
        const int m = mt + ty + k;
        const int srow = blockIdx.z * NN + m;
        const float v = Sb[(size_t)m * NN + nt + tx];
        t[ty + k][tx] = __expf(v - stats[srow]) * stats[statR + srow];
    }
    __syncthreads();
    #pragma unroll
    for (int k = 0; k < 32; k += 8)
        Pb[(size_t)(nt + ty + k) * NN + mt + tx] = f2bf(t[tx][ty + k]);
}

extern "C" void kernel_launch(void* const* d_in, const int* in_sizes, int n_in,
                              void* d_out, int out_size, void* d_ws, size_t ws_size,
                              hipStream_t stream)
{
    const float* x      = (const float*)d_in[0];
    const float* weight = (const float*)d_in[1];
    const float* bias   = (const float*)d_in[2];
    const float* w_one  = (const float*)d_in[3];
    const float* w_two  = (const float*)d_in[4];
    float* out = (float*)d_out;

    const long NF  = (long)NN * FF;    // 1,048,576
    const long NN2 = (long)NN * NN;    // 4,194,304
    const long FF2 = (long)FF * FF;

    // workspace carve (bf16 = unsigned short)
    char* p = (char*)d_ws;
    unsigned short* xb   = (unsigned short*)p; p += BB * NF * 2;
    unsigned short* w1b  = (unsigned short*)p; p += FF2 * 2;
    unsigned short* w2b  = (unsigned short*)p; p += FF2 * 2;
    unsigned short* wTb  = (unsigned short*)p; p += FF2 * 2;
    unsigned short* supT = (unsigned short*)p; p += BB * NF * 2;
    unsigned short* p1   = (unsigned short*)p; p += BB * NF * 2;
    unsigned short* p2   = (unsigned short*)p; p += BB * NF * 2;

    const size_t fixed = (size_t)(p - (char*)d_ws);
    const size_t need_full  = fixed + (size_t)BB * NN2 * 2   // P
                            + (size_t)2 * BB * NN * 4        // stats
                            + (size_t)BB * NN2 * 4;          // S
    const size_t need_batch = fixed + (size_t)NN2 * 2 + (size_t)2 * NN * 4 + (size_t)NN2 * 4;

    dim3 blk(256);

    // --- common: convert inputs to bf16 ---
    convert_bf16<<<dim3((BB * NF) / (8 * 256)), blk, 0, stream>>>(x, xb, BB * NF);
    convert_bf16<<<dim3(FF2 / (8 * 256)), blk, 0, stream>>>(w_one, w1b, FF2);
    convert_bf16<<<dim3(FF2 / (8 * 256)), blk, 0, stream>>>(w_two, w2b, FF2);
    transpose_convert<<<dim3(FF / 32, FF / 32), blk, 0, stream>>>(weight, wTb, FF);

    // supT[o,m] = sum_f wT[o,f] * xb[m,f]   (bf16 out)
    gemm_mfma_bt<<<dim3(NN / 128, FF / 128, BB), blk, 0, stream>>>(
        wTb, xb, supT, nullptr, FF, NN, FF, 0, NF, NF, 1);
    // p1[n,e] = sum_f xb[n,f] * w1b[e,f]    (bf16 out)
    gemm_mfma_bt<<<dim3(FF / 128, NN / 128, BB), blk, 0, stream>>>(
        xb, w1b, p1, nullptr, NN, FF, FF, NF, 0, NF, 1);
    // p2[n,e] = sum_f xb[n,f] * w2b[e,f]    (bf16 out)
    gemm_mfma_bt<<<dim3(FF / 128, NN / 128, BB), blk, 0, stream>>>(
        xb, w2b, p2, nullptr, NN, FF, FF, NF, 0, NF, 1);

    if (ws_size >= need_full) {
        unsigned short* P = (unsigned short*)p;
        float* stats = (float*)(p + (size_t)BB * NN2 * 2);
        float* S     = (float*)(p + (size_t)BB * NN2 * 2 + (size_t)2 * BB * NN * 4);

        // S[m,n] = sum_e p2[m,e] p1[n,e]   (fp32 out)
        gemm_mfma_bt<<<dim3(NN / 128, NN / 128, BB), blk, 0, stream>>>(
            p2, p1, S, nullptr, NN, NN, FF, NF, NF, NN2, 0);
        row_stats<<<dim3(BB * NN), blk, 0, stream>>>(S, stats, NN);
        softmax_transpose<<<dim3(NN / 32, NN / 32, BB), blk, 0, stream>>>(
            S, stats, P, BB * NN);
        // out[n,o] = sum_m P[n,m] supT[o,m] + bias[o]   (fp32 out)
        gemm_mfma_bt<<<dim3(FF / 128, NN / 128, BB), blk, 0, stream>>>(
            P, supT, out, bias, NN, FF, NN, NN2, NF, NF, 0);
    } else {
        // per-batch S/P (needs ~94 MB total)
        unsigned short* P = (unsigned short*)p;
        float* stats = (float*)(p + (size_t)NN2 * 2);
        float* S     = (float*)(p + (size_t)NN2 * 2 + (size_t)2 * NN * 4);
        (void)need_batch;
        for (int b = 0; b < BB; ++b) {
            gemm_mfma_bt<<<dim3(NN / 128, NN / 128, 1), blk, 0, stream>>>(
                p2 + (long)b * NF, p1 + (long)b * NF, S, nullptr, NN, NN, FF, 0, 0, 0, 0);
            row_stats<<<dim3(NN), blk, 0, stream>>>(S, stats, NN);
            softmax_transpose<<<dim3(NN / 32, NN / 32, 1), blk, 0, stream>>>(
                S, stats, P, NN);
            gemm_mfma_bt<<<dim3(FF / 128, NN / 128, 1), blk, 0, stream>>>(
                P, supT + (long)b * NF, out + (long)b * NF, bias, NN, FF, NN, 0, 0, 0, 0);
        }
    }
}

// Round 3
// 264.699 us; speedup vs baseline: 7.8389x; 2.7716x over previous
//
#include <hip/hip_runtime.h>
#include <math.h>

// B=8, N=2048, Fin=Fout=512, fp32 in/out. bf16 MFMA internally.
// out[n,o] = sum_m exp(adj[n,m]) * (sup[m,o] / D[m]),  D[m] = sum_n exp(adj[n,m])
#define BB 8
#define NN 2048
#define FF 512

typedef __attribute__((ext_vector_type(8))) short short8;
typedef __attribute__((ext_vector_type(4))) float floatx4;

__device__ __forceinline__ unsigned short f2bf(float f) {
    union { float f; unsigned u; } v; v.f = f;
    unsigned r = v.u + 0x7FFFu + ((v.u >> 16) & 1u);
    return (unsigned short)(r >> 16);
}

// ---------------------------------------------------------------------------
// BT-GEMM, bf16 MFMA: C[i,j] = sum_k A[i*a_ld+k] * B[j*b_ld+k]
// modes: 0 = fp32 out + bias[j]; 1 = bf16 out; 2 = bf16 exp(out) + colsum atomics->Dsum
// 128x128 tile, BK=32, 256 thr = 4 waves (2x2), 4x4 16x16x32 frags/wave.
// ---------------------------------------------------------------------------
__global__ __launch_bounds__(256) void gemm_mfma_bt(
    const unsigned short* __restrict__ A, const unsigned short* __restrict__ B,
    void* __restrict__ Cv, const float* __restrict__ bias, float* __restrict__ Dsum,
    int M, int Nc, int K, int a_ld, int b_ld, int ldc,
    long a_batch, long b_batch, long c_batch, int mode)
{
    __shared__ __align__(16) unsigned short Alds[128 * 32];
    __shared__ __align__(16) unsigned short Blds[128 * 32];

    const int tid  = threadIdx.x;
    const int wave = tid >> 6;
    const int lane = tid & 63;
    const int bz   = blockIdx.z;

    const unsigned short* Ab = A + (long)bz * a_batch;
    const unsigned short* Bb = B + (long)bz * b_batch;

    const int m0 = blockIdx.y * 128;
    const int n0 = blockIdx.x * 128;

    const int wm   = (wave >> 1) * 64;
    const int wn   = (wave & 1) * 64;
    const int fl   = lane & 15;
    const int quad = lane >> 4;

    floatx4 acc[4][4] = {};

    for (int k0 = 0; k0 < K; k0 += 32) {
        #pragma unroll
        for (int issue = 0; issue < 2; ++issue) {
            const int cbase = issue * 256 + wave * 64;
            const int c = cbase + lane;
            const int row = c >> 2, kq = (c & 3) * 8;
            const unsigned short* gA = Ab + (long)(m0 + row) * a_ld + k0 + kq;
            __builtin_amdgcn_global_load_lds(
                (const __attribute__((address_space(1))) void*)gA,
                (__attribute__((address_space(3))) void*)&Alds[cbase * 8], 16, 0, 0);
            const unsigned short* gB = Bb + (long)(n0 + row) * b_ld + k0 + kq;
            __builtin_amdgcn_global_load_lds(
                (const __attribute__((address_space(1))) void*)gB,
                (__attribute__((address_space(3))) void*)&Blds[cbase * 8], 16, 0, 0);
        }
        __syncthreads();

        short8 af[4], bf[4];
        #pragma unroll
        for (int i = 0; i < 4; ++i)
            af[i] = *(const short8*)&Alds[(wm + i * 16 + fl) * 32 + quad * 8];
        #pragma unroll
        for (int j = 0; j < 4; ++j)
            bf[j] = *(const short8*)&Blds[(wn + j * 16 + fl) * 32 + quad * 8];

        #pragma unroll
        for (int i = 0; i < 4; ++i)
            #pragma unroll
            for (int j = 0; j < 4; ++j)
                acc[i][j] = __builtin_amdgcn_mfma_f32_16x16x32_bf16(af[i], bf[j], acc[i][j], 0, 0, 0);
        __syncthreads();
    }

    // C/D layout: col = lane&15, row = quad*4 + reg (verified m89/m91).
    if (mode == 0) {
        float* Cb = (float*)Cv + (long)bz * c_batch;
        #pragma unroll
        for (int j = 0; j < 4; ++j) {
            const int ng = n0 + wn + j * 16 + fl;
            const float badd = bias ? bias[ng] : 0.0f;
            #pragma unroll
            for (int i = 0; i < 4; ++i) {
                const int mg = m0 + wm + i * 16 + quad * 4;
                #pragma unroll
                for (int r = 0; r < 4; ++r)
                    Cb[(long)(mg + r) * ldc + ng] = acc[i][j][r] + badd;
            }
        }
    } else if (mode == 1) {
        unsigned short* Cb = (unsigned short*)Cv + (long)bz * c_batch;
        #pragma unroll
        for (int j = 0; j < 4; ++j) {
            const int ng = n0 + wn + j * 16 + fl;
            #pragma unroll
            for (int i = 0; i < 4; ++i) {
                const int mg = m0 + wm + i * 16 + quad * 4;
                #pragma unroll
                for (int r = 0; r < 4; ++r)
                    Cb[(long)(mg + r) * ldc + ng] = f2bf(acc[i][j][r]);
            }
        }
    } else {
        // mode 2: E = exp(acc) bf16; Dsum[col] += column partial sums.
        unsigned short* Cb = (unsigned short*)Cv + (long)bz * c_batch;
        float* Db = Dsum + (long)bz * NN;
        #pragma unroll
        for (int j = 0; j < 4; ++j) {
            const int ng = n0 + wn + j * 16 + fl;
            float csum = 0.f;
            #pragma unroll
            for (int i = 0; i < 4; ++i) {
                const int mg = m0 + wm + i * 16 + quad * 4;
                #pragma unroll
                for (int r = 0; r < 4; ++r) {
                    const float e = __expf(acc[i][j][r]);
                    csum += e;
                    Cb[(long)(mg + r) * ldc + ng] = f2bf(e);
                }
            }
            csum += __shfl_xor(csum, 16);
            csum += __shfl_xor(csum, 32);
            if (quad == 0) atomicAdd(&Db[ng], csum);
        }
    }
}

// fused fp32->bf16 convert for x, w_one, w_two (8 elems/thread, region split)
__global__ __launch_bounds__(256) void convert_all(
    const float* __restrict__ x, const float* __restrict__ w1, const float* __restrict__ w2,
    unsigned short* __restrict__ xb, unsigned short* __restrict__ w1b, unsigned short* __restrict__ w2b)
{
    const long NX = (long)BB * NN * FF / 8;   // 1,048,576 chunks
    const long NW = (long)FF * FF / 8;        // 32,768 chunks
    long t = (long)blockIdx.x * 256 + threadIdx.x;
    const float* in; unsigned short* out;
    if (t < NX) { in = x; out = xb; }
    else if (t < NX + NW) { in = w1; out = w1b; t -= NX; }
    else if (t < NX + 2 * NW) { in = w2; out = w2b; t -= NX + NW; }
    else return;
    const long i = t * 8;
    float4 a = *(const float4*)(in + i);
    float4 b = *(const float4*)(in + i + 4);
    short8 o;
    o[0] = (short)f2bf(a.x); o[1] = (short)f2bf(a.y);
    o[2] = (short)f2bf(a.z); o[3] = (short)f2bf(a.w);
    o[4] = (short)f2bf(b.x); o[5] = (short)f2bf(b.y);
    o[6] = (short)f2bf(b.z); o[7] = (short)f2bf(b.w);
    *(short8*)(out + i) = o;
}

// out[o,f] = bf16(in[f,o]) for dim x dim fp32 (dim % 32 == 0)
__global__ __launch_bounds__(256) void transpose_convert(
    const float* __restrict__ in, unsigned short* __restrict__ out, int dim)
{
    __shared__ float t[32][33];
    const int tx = threadIdx.x & 31, ty = threadIdx.x >> 5;
    const int x0 = blockIdx.x * 32, y0 = blockIdx.y * 32;
    #pragma unroll
    for (int k = 0; k < 32; k += 8)
        t[ty + k][tx] = in[(long)(y0 + ty + k) * dim + x0 + tx];
    __syncthreads();
    #pragma unroll
    for (int k = 0; k < 32; k += 8)
        out[(long)(x0 + ty + k) * dim + y0 + tx] = f2bf(t[tx][ty + k]);
}

__global__ __launch_bounds__(256) void zero_f32(float* __restrict__ p, long n)
{
    long i = (long)blockIdx.x * 256 + threadIdx.x;
    if (i < n) p[i] = 0.0f;
}

// supT'[o,m] = bf16( sup[m,o] / D[m] ); sup[m,o] = Call[m*1536 + 1024 + o] (bf16).
// grid: (NN/32, FF/32, batches). batch0 selects Call/D/out batch offset base.
__global__ __launch_bounds__(256) void scale_transpose(
    const unsigned short* __restrict__ Call, const float* __restrict__ D,
    unsigned short* __restrict__ supT, int batch0)
{
    __shared__ float t[32][33];
    __shared__ float rD[32];
    const int tx = threadIdx.x & 31, ty = threadIdx.x >> 5;
    const int mt = blockIdx.x * 32, ot = blockIdx.y * 32;
    const int b = batch0 + blockIdx.z;
    const unsigned short* Cb = Call + (long)b * NN * 1536;
    unsigned short* Tb = supT + (long)b * NN * FF;
    if (threadIdx.x < 32) rD[threadIdx.x] = 1.0f / D[(long)b * NN + mt + threadIdx.x];
    #pragma unroll
    for (int k = 0; k < 32; k += 8) {
        unsigned short u = Cb[(long)(mt + ty + k) * 1536 + 1024 + ot + tx];
        union { unsigned u; float f; } cv; cv.u = ((unsigned)u) << 16;
        t[ty + k][tx] = cv.f;
    }
    __syncthreads();
    #pragma unroll
    for (int k = 0; k < 32; k += 8)
        Tb[(long)(ot + ty + k) * NN + mt + tx] = f2bf(t[tx][ty + k] * rD[tx]);
}

extern "C" void kernel_launch(void* const* d_in, const int* in_sizes, int n_in,
                              void* d_out, int out_size, void* d_ws, size_t ws_size,
                              hipStream_t stream)
{
    const float* x      = (const float*)d_in[0];
    const float* weight = (const float*)d_in[1];
    const float* bias   = (const float*)d_in[2];
    const float* w_one  = (const float*)d_in[3];
    const float* w_two  = (const float*)d_in[4];
    float* out = (float*)d_out;

    const long NF  = (long)NN * FF;      // 1,048,576
    const long NN2 = (long)NN * NN;      // 4,194,304
    const long CROW = 1536;              // C_all row stride (p1|p2|sup)

    // workspace carve
    char* p = (char*)d_ws;
    unsigned short* xb    = (unsigned short*)p; p += (size_t)BB * NF * 2;          // 16 MB
    unsigned short* Wall  = (unsigned short*)p; p += (size_t)CROW * FF * 2;        // 1.5 MB
    unsigned short* Call  = (unsigned short*)p; p += (size_t)BB * NN * CROW * 2;   // 48 MB
    unsigned short* supT  = (unsigned short*)p; p += (size_t)BB * NF * 2;          // 16 MB
    float*          Dsum  = (float*)p;          p += (size_t)BB * NN * 4;          // 64 KB
    unsigned short* E     = (unsigned short*)p;                                    // 64 MB (full) or 8 MB (batch)
    unsigned short* w1b = Wall;
    unsigned short* w2b = Wall + (size_t)FF * FF;
    unsigned short* wTb = Wall + (size_t)2 * FF * FF;

    const size_t fixed = (size_t)(p - (char*)d_ws);
    const bool full = ws_size >= fixed + (size_t)BB * NN2 * 2;

    dim3 blk(256);

    // 1) converts
    convert_all<<<dim3(4352), blk, 0, stream>>>(x, w_one, w_two, xb, w1b, w2b);
    transpose_convert<<<dim3(FF / 32, FF / 32), blk, 0, stream>>>(weight, wTb, FF);
    zero_f32<<<dim3((BB * NN) / 256), blk, 0, stream>>>(Dsum, BB * NN);

    // 2) C_all[n, :] = [p1 | p2 | sup]: BT(xb, Wall), M=2048, Nc=1536, K=512
    gemm_mfma_bt<<<dim3(CROW / 128, NN / 128, BB), blk, 0, stream>>>(
        xb, Wall, Call, nullptr, nullptr, NN, CROW, FF,
        FF, FF, CROW, NF, 0, NN * CROW, 1);

    if (full) {
        // 3) E[n,m] = exp(BT(p1, p2)), Dsum[b,m] += colsums
        gemm_mfma_bt<<<dim3(NN / 128, NN / 128, BB), blk, 0, stream>>>(
            Call, Call + FF, E, nullptr, Dsum, NN, NN, FF,
            CROW, CROW, NN, NN * CROW, NN * CROW, NN2, 2);
        // 4) supT'[o,m] = sup[m,o]/D[m]
        scale_transpose<<<dim3(NN / 32, FF / 32, BB), blk, 0, stream>>>(Call, Dsum, supT, 0);
        // 5) out[n,o] = BT(E, supT') + bias, K = 2048
        gemm_mfma_bt<<<dim3(FF / 128, NN / 128, BB), blk, 0, stream>>>(
            E, supT, out, bias, nullptr, NN, FF, NN,
            NN, NN, FF, NN2, NF, NF, 0);
    } else {
        for (int b = 0; b < BB; ++b) {
            const unsigned short* Cb = Call + (size_t)b * NN * CROW;
            gemm_mfma_bt<<<dim3(NN / 128, NN / 128, 1), blk, 0, stream>>>(
                Cb, Cb + FF, E, nullptr, Dsum + (size_t)b * NN, NN, NN, FF,
                CROW, CROW, NN, 0, 0, 0, 2);
            scale_transpose<<<dim3(NN / 32, FF / 32, 1), blk, 0, stream>>>(Call, Dsum, supT, b);
            gemm_mfma_bt<<<dim3(FF / 128, NN / 128, 1), blk, 0, stream>>>(
                E, supT + (size_t)b * NF, out + (size_t)b * NF, bias, nullptr, NN, FF, NN,
                NN, NN, FF, 0, 0, 0, 0);
        }
    }
}